// Round 11
// baseline (427.143 us; speedup 1.0000x reference)
//
#include <hip/hip_runtime.h>
#include <math.h>

namespace {

constexpr int N_ = 1024;
constexpr int M_ = 1024;
constexpr int C_ = 64;
constexpr unsigned NBLK = 512;   // need 2 blocks/CU; LDS allows 4/CU -> 2x margin

typedef _Float16 f16x8 __attribute__((ext_vector_type(8)));
typedef __fp16 fp16x2 __attribute__((ext_vector_type(2)));   // cvt_pkrtz native type
typedef float f32x4 __attribute__((ext_vector_type(4)));

__device__ __forceinline__ float sig(float x) { return 1.0f / (1.0f + expf(-x)); }

__device__ __forceinline__ unsigned flipbits(float f) {
    unsigned u = __float_as_uint(f);
    return u ^ (0x80000000u | (unsigned)((int)u >> 31));
}
__device__ __forceinline__ float unflipbits(unsigned k) {
    unsigned u = (k & 0x80000000u) ? (k ^ 0x80000000u) : ~k;
    return __uint_as_float(u);
}
__device__ __forceinline__ unsigned long long packlogit(float v, unsigned idx) {
    return ((unsigned long long)flipbits(v) << 32) | (unsigned)(0xFFFFFFFFu - idx);
}
__device__ __forceinline__ unsigned long long packpos(float v, unsigned idx) {
    return ((unsigned long long)__float_as_uint(v) << 32) | (unsigned)(0xFFFFFFFFu - idx);
}
__device__ __forceinline__ unsigned long long shflx64(unsigned long long v, int m) {
    unsigned lo = __shfl_xor((unsigned)v, m);
    unsigned hi = __shfl_xor((unsigned)(v >> 32), m);
    return ((unsigned long long)hi << 32) | lo;
}

// hand-rolled grid barrier (counters zeroed by hipMemsetAsync before launch).
// release fence + device-scope arrive; acquire spin; acquire fence.
__device__ __forceinline__ void gridbar(unsigned* bar, unsigned target) {
    __syncthreads();
    if (threadIdx.x == 0) {
        __threadfence();    // agent-scope release of this block's stores
        __hip_atomic_fetch_add(bar, 1u, __ATOMIC_RELEASE, __HIP_MEMORY_SCOPE_AGENT);
        while (__hip_atomic_load(bar, __ATOMIC_ACQUIRE, __HIP_MEMORY_SCOPE_AGENT) < target)
            __builtin_amdgcn_s_sleep(4);
        __threadfence();    // agent-scope acquire: drop stale cached lines
    }
    __syncthreads();
}

// phase-overlaid LDS (union): biggest is phase B at 37.75 KB
struct SmemA { float XA[4][C_ + 1]; float XB[4][C_ + 1]; float W[C_ * C_]; float Bv[C_]; };
struct SmemB {
    float SU[32][68];                 // 8704 B
    float SVB[2][32][68];             // 17408 B (both zz staged once)
    float OUTT[32][33][2];            // 8448 B
    unsigned long long RED[8][32][2]; // 4096 B
};
struct SmemC { float h1s[4][C_]; };
union Smem { SmemA a; SmemB b; SmemC c; };

__global__ __launch_bounds__(256, 4) void fused_kernel(
    const float* __restrict__ step_x, const float* __restrict__ state_x,
    const float* __restrict__ w1, const float* __restrict__ b1,
    const float* __restrict__ w2, const float* __restrict__ b2,
    const float* __restrict__ w3, const float* __restrict__ b3,
    const float* __restrict__ pw1, const float* __restrict__ pb1,
    const float* __restrict__ pw2, const float* __restrict__ pb2,
    const float* __restrict__ pw3, const float* __restrict__ pb3,
    float* __restrict__ U, _Float16* __restrict__ w2T,
    unsigned long long* __restrict__ rowbest,
    float* __restrict__ out, unsigned long long* __restrict__ PT2,
    unsigned* __restrict__ bar)
{
    __shared__ Smem sm;
    const int t = threadIdx.x;
    const int bid = blockIdx.x;

    // ========== Phase A: pre-MLP (4 rows/block over 512 blocks) + w2T prep ==
    {
        SmemA& A = sm.a;
        const int r0 = bid * 4;            // rows r0..r0+3 (4 | 1024: no straddle)
        if (t < 64) {
            int rr = t >> 4, k4 = (t & 15) << 2;
            int row = r0 + rr;
            const float* src = (row < N_) ? (step_x + (size_t)row * C_ + k4)
                                          : (state_x + (size_t)(row - N_) * C_ + k4);
            float4 v = *reinterpret_cast<const float4*>(src);
            A.XA[rr][k4 + 0] = v.x; A.XA[rr][k4 + 1] = v.y;
            A.XA[rr][k4 + 2] = v.z; A.XA[rr][k4 + 3] = v.w;
        }
        if (bid >= 480 && bid < 496) {     // w2 -> transposed f16 (16 blocks)
            int e = (bid - 480) * 256 + t;
            w2T[(e & 63) * 64 + (e >> 6)] = (_Float16)pw2[e];
        }
        // rowbest + bar zeroed by the pre-launch hipMemsetAsync

        const float* Ws[4] = {w1, w2, w3, pw1};
        const float* Bs[4] = {b1, b2, b3, nullptr};
        float (*sA)[C_ + 1] = A.XA;
        float (*sB)[C_ + 1] = A.XB;
        const int c = t & 63;
        const int row = t >> 6;            // 0..3, one row per 64-thread group
        for (int layer = 0; layer < 4; ++layer) {
            __syncthreads();
            for (int e = t; e < C_ * C_ / 4; e += 256)
                reinterpret_cast<float4*>(A.W)[e] =
                    reinterpret_cast<const float4*>(Ws[layer])[e];
            if (t < C_) A.Bv[t] = (layer == 3) ? 0.0f : Bs[layer][t];
            __syncthreads();
            float acc = A.Bv[c];
            #pragma unroll 8
            for (int k = 0; k < C_; ++k)
                acc = fmaf(sA[row][k], A.W[k * C_ + c], acc);
            sB[row][c] = (layer < 2) ? fmaxf(acc, 0.0f) : acc;
            float (*tmp)[C_ + 1] = sA; sA = sB; sB = tmp;
        }
        U[(size_t)(r0 + row) * C_ + c] = sA[row][c];  // own writes only
    }
    gridbar(bar + 0, NBLK);

    // ========== Phase B: pair MLP, 2 tile-positions x 2 zz per block ========
    {
        SmemB& B = sm.b;
        const int lane = t & 63;
        const int wave = t >> 6;
        const int wi = wave >> 1, wj = wave & 1;
        const int ch_l = lane & 15;
        const int kg = lane >> 4;

        f16x8 whi[4][2];
        #pragma unroll
        for (int mt = 0; mt < 4; ++mt)
            #pragma unroll
            for (int ks = 0; ks < 2; ++ks)
                whi[mt][ks] = *reinterpret_cast<const f16x8*>(
                    w2T + (mt * 16 + ch_l) * 64 + ks * 32 + kg * 8);

        float b2v[16], w30[16], w31[16];
        #pragma unroll
        for (int mt = 0; mt < 4; ++mt)
            #pragma unroll
            for (int r = 0; r < 4; ++r) {
                int ch = mt * 16 + kg * 4 + r;
                b2v[mt * 4 + r] = pb2[ch];
                w30[mt * 4 + r] = pw3[ch * 2];
                w31[mt * 4 + r] = pw3[ch * 2 + 1];
            }
        const float ob0 = pb3[0], ob1 = pb3[1];

        for (int p = 0; p < 2; ++p) {
            const int tp = bid + p * 512;          // tile position 0..1023
            const int ibase = (tp >> 5) * 32;
            const int jbase = (tp & 31) * 32;

            __syncthreads();                       // protect LDS reuse across p
            {   // stage SU + SVB[0] (step) + SVB[1] (state), pb1 folded in
                const int r = t >> 3, k0 = (t & 7) * 8;
                const float* up = U + (size_t)(ibase + r) * C_ + k0;
                *reinterpret_cast<float4*>(&B.SU[r][k0])     = *reinterpret_cast<const float4*>(up);
                *reinterpret_cast<float4*>(&B.SU[r][k0 + 4]) = *reinterpret_cast<const float4*>(up + 4);
                float4 c0 = *reinterpret_cast<const float4*>(pb1 + k0);
                float4 c1 = *reinterpret_cast<const float4*>(pb1 + k0 + 4);
                #pragma unroll
                for (int zzv = 0; zzv < 2; ++zzv) {
                    const float* vp = U + (size_t)(zzv * N_ + jbase + r) * C_ + k0;
                    float4 b0 = *reinterpret_cast<const float4*>(vp);
                    float4 b1v = *reinterpret_cast<const float4*>(vp + 4);
                    b0.x += c0.x; b0.y += c0.y; b0.z += c0.z; b0.w += c0.w;
                    b1v.x += c1.x; b1v.y += c1.y; b1v.z += c1.z; b1v.w += c1.w;
                    *reinterpret_cast<float4*>(&B.SVB[zzv][r][k0])     = b0;
                    *reinterpret_cast<float4*>(&B.SVB[zzv][r][k0 + 4]) = b1v;
                }
            }
            __syncthreads();

            float su[2][8];
            #pragma unroll
            for (int ks = 0; ks < 2; ++ks) {
                int k0 = ks * 32 + kg * 8;
                float4 a = *reinterpret_cast<const float4*>(&B.SU[wi * 16 + ch_l][k0]);
                float4 b = *reinterpret_cast<const float4*>(&B.SU[wi * 16 + ch_l][k0 + 4]);
                su[ks][0] = a.x; su[ks][1] = a.y; su[ks][2] = a.z; su[ks][3] = a.w;
                su[ks][4] = b.x; su[ks][5] = b.y; su[ks][6] = b.z; su[ks][7] = b.w;
            }

            for (int zzv = 0; zzv < 2; ++zzv) {
                if (zzv) __syncthreads();          // protect OUTT reuse across zz
                for (int jj = 0; jj < 16; ++jj) {
                    const int jr = wj * 16 + jj;
                    f16x8 bhi[2];
                    #pragma unroll
                    for (int ks = 0; ks < 2; ++ks) {
                        int k0 = ks * 32 + kg * 8;
                        float4 a = *reinterpret_cast<const float4*>(&B.SVB[zzv][jr][k0]);
                        float4 b = *reinterpret_cast<const float4*>(&B.SVB[zzv][jr][k0 + 4]);
                        float sv[8] = {a.x, a.y, a.z, a.w, b.x, b.y, b.z, b.w};
                        union { f16x8 v; fp16x2 h2[4]; } bu;
                        #pragma unroll
                        for (int m = 0; m < 4; ++m) {
                            float x0 = fmaxf(su[ks][2 * m]     + sv[2 * m],     0.0f);
                            float x1 = fmaxf(su[ks][2 * m + 1] + sv[2 * m + 1], 0.0f);
                            bu.h2[m] = __builtin_amdgcn_cvt_pkrtz(x0, x1);
                        }
                        bhi[ks] = bu.v;
                    }
                    f32x4 ah[4];
                    #pragma unroll
                    for (int mt = 0; mt < 4; ++mt)
                        ah[mt] = f32x4{b2v[4 * mt], b2v[4 * mt + 1], b2v[4 * mt + 2], b2v[4 * mt + 3]};
                    #pragma unroll
                    for (int ks = 0; ks < 2; ++ks)
                        #pragma unroll
                        for (int mt = 0; mt < 4; ++mt)
                            ah[mt] = __builtin_amdgcn_mfma_f32_16x16x32_f16(whi[mt][ks], bhi[ks], ah[mt], 0, 0, 0);
                    float p0 = 0.0f, p1 = 0.0f;
                    #pragma unroll
                    for (int mt = 0; mt < 4; ++mt)
                        #pragma unroll
                        for (int r = 0; r < 4; ++r) {
                            float g = fmaxf(ah[mt][r], 0.0f);
                            p0 = fmaf(g, w30[4 * mt + r], p0);
                            p1 = fmaf(g, w31[4 * mt + r], p1);
                        }
                    p0 += __shfl_xor(p0, 16); p0 += __shfl_xor(p0, 32);
                    p1 += __shfl_xor(p1, 16); p1 += __shfl_xor(p1, 32);
                    if (lane < 16) {
                        B.OUTT[wi * 16 + lane][wj * 16 + jj][0] = p0 + ob0;
                        B.OUTT[wi * 16 + lane][wj * 16 + jj][1] = p1 + ob1;
                    }
                }
                __syncthreads();
                {   // writeout tile
                    float* obase = out + (size_t)zzv * (2ull * N_ * M_);
                    int r = t >> 3;
                    int q0 = (t & 7) * 4;
                    int i = ibase + r;
                    #pragma unroll
                    for (int q = 0; q < 4; ++q) {
                        int j = jbase + q0 + q;
                        float2 v = *reinterpret_cast<float2*>(&B.OUTT[r][q0 + q][0]);
                        *reinterpret_cast<float2*>(obase + ((size_t)i * M_ + j) * 2) = v;
                    }
                }
                if (zzv) {   // fused column top-2 over this tile's 32 rows (st logit)
                    const int tc = t & 31, tg = t >> 5;
                    unsigned long long k1 = 0, k2 = 0;
                    #pragma unroll
                    for (int q = 0; q < 4; ++q) {
                        int r = tg * 4 + q;
                        unsigned long long k = packlogit(B.OUTT[r][tc][0], (unsigned)(ibase + r));
                        if (k > k1) { k2 = k1; k1 = k; } else if (k > k2) k2 = k;
                    }
                    B.RED[tg][tc][0] = k1; B.RED[tg][tc][1] = k2;
                    for (int h = 4; h > 0; h >>= 1) {
                        __syncthreads();
                        if (tg < h) {
                            unsigned long long a = B.RED[tg + h][tc][0], b = B.RED[tg + h][tc][1];
                            if (a > k1) { k2 = k1; k1 = a; } else if (a > k2) k2 = a;
                            if (b > k1) { k2 = k1; k1 = b; } else if (b > k2) k2 = b;
                            B.RED[tg][tc][0] = k1; B.RED[tg][tc][1] = k2;
                        }
                    }
                    if (tg == 0) {
                        size_t o = ((size_t)(tp >> 5) * M_ + (jbase + tc)) * 2;
                        PT2[o] = k1; PT2[o + 1] = k2;
                    }
                }
            }
        }
    }
    gridbar(bar + 1, NBLK);

    // ========== Phase C: column finalize (blocks 0..255, 4 cols each) =======
    if (bid < 256) {
        SmemC& Cc = sm.c;
        const int w = t >> 6, lane = t & 63;
        const int j = bid * 4 + w;

        unsigned long long k1 = PT2[((size_t)(lane >> 1) * M_ + j) * 2 + (lane & 1)];
        unsigned long long k2 = 0;
        #pragma unroll
        for (int m = 1; m < 64; m <<= 1) {
            unsigned long long a = shflx64(k1, m), b = shflx64(k2, m);
            if (a > k1) { k2 = k1; k1 = a; } else if (a > k2) k2 = a;
            if (b > k1) { k2 = k1; k1 = b; } else if (b > k2) k2 = b;
        }
        int ids[2];
        ids[0] = (int)(0xFFFFFFFFu - (unsigned)(k1 & 0xFFFFFFFFull));
        int i2 = (int)(0xFFFFFFFFu - (unsigned)(k2 & 0xFFFFFFFFull));
        float v1 = unflipbits((unsigned)(k1 >> 32));
        float v2 = unflipbits((unsigned)(k2 >> 32));
        // uniform 2 candidates (dup winner when no near-tie): __syncthreads legal
        ids[1] = (v1 - v2 < 8e-3f) ? i2 : ids[0];

        float logits[2];
        #pragma unroll
        for (int cnd = 0; cnd < 2; ++cnd) {
            int i = ids[cnd];
            Cc.h1s[w][lane] = fmaxf(U[(size_t)i * C_ + lane] + U[(size_t)(N_ + j) * C_ + lane] + pb1[lane], 0.0f);
            __syncthreads();
            float acc = pb2[lane];
            #pragma unroll 8
            for (int k = 0; k < 64; ++k)
                acc = fmaf(Cc.h1s[w][k], pw2[k * 64 + lane], acc);
            float p = fmaxf(acc, 0.0f) * pw3[lane * 2];
            #pragma unroll
            for (int m = 1; m < 64; m <<= 1) p += __shfl_xor(p, m);
            logits[cnd] = p + pb3[0];
            __syncthreads();
        }
        int wi2; float wp;
        if (logits[0] > logits[1])      { wi2 = ids[0]; wp = logits[0]; }
        else if (logits[1] > logits[0]) { wi2 = ids[1]; wp = logits[1]; }
        else                            { wi2 = min(ids[0], ids[1]); wp = logits[0]; }
        if (lane == 0)
            atomicMax(&rowbest[wi2], packpos(sig(wp), (unsigned)j));
    }
    gridbar(bar + 2, NBLK);

    // ========== Phase D: zero matched rows + scatter mutual matches =========
    {
        float* matched = out + 4ull * N_ * M_;
        #pragma unroll
        for (int rr = 0; rr < 2; ++rr) {
            int i = bid * 2 + rr;
            *reinterpret_cast<float4*>(matched + (size_t)i * M_ + t * 4) =
                float4{0.0f, 0.0f, 0.0f, 0.0f};
        }
        __syncthreads();
        if (t < 2) {
            int i = bid * 2 + t;
            unsigned long long key = rowbest[i];
            if (key) {
                unsigned j = 0xFFFFFFFFu - (unsigned)(key & 0xFFFFFFFFull);
                matched[(size_t)i * M_ + j] = __uint_as_float((unsigned)(key >> 32));
            }
        }
    }
}

} // namespace

extern "C" void kernel_launch(void* const* d_in, const int* in_sizes, int n_in,
                              void* d_out, int out_size, void* d_ws, size_t ws_size,
                              hipStream_t stream)
{
    const float* step_x  = (const float*)d_in[0];
    const float* state_x = (const float*)d_in[1];
    const float* pre_w1  = (const float*)d_in[2];
    const float* pre_b1  = (const float*)d_in[3];
    const float* pre_w2  = (const float*)d_in[4];
    const float* pre_b2  = (const float*)d_in[5];
    const float* pre_w3  = (const float*)d_in[6];
    const float* pre_b3  = (const float*)d_in[7];
    const float* post_w1 = (const float*)d_in[8];
    const float* post_b1 = (const float*)d_in[9];
    const float* post_w2 = (const float*)d_in[10];
    const float* post_b2 = (const float*)d_in[11];
    const float* post_w3 = (const float*)d_in[12];
    const float* post_b3 = (const float*)d_in[13];

    float* out     = (float*)d_out;
    float* matched = out + 4ull * N_ * M_;

    // ws: U (512KB) + rowbest (8KB) + barrier counters (12B)
    float* U = (float*)d_ws;
    unsigned long long* rowbest = (unsigned long long*)((char*)d_ws + 512 * 1024);
    unsigned* bar = (unsigned*)((char*)d_ws + 520 * 1024);

    // scratch inside 'matched' (4MB), fully consumed before phase D rewrites it
    unsigned long long* PT2 = (unsigned long long*)matched;       // 512KB (B->C)
    _Float16* w2T = (_Float16*)((char*)matched + 512 * 1024);     // 8KB  (A->B)

    // zero rowbest + barrier counters (capturable memset node)
    hipMemsetAsync((char*)d_ws + 512 * 1024, 0, 8 * 1024 + 16, stream);

    hipLaunchKernelGGL(fused_kernel, dim3(NBLK), dim3(256), 0, stream,
        step_x, state_x, pre_w1, pre_b1, pre_w2, pre_b2, pre_w3, pre_b3,
        post_w1, post_b1, post_w2, post_b2, post_w3, post_b3,
        U, w2T, rowbest, out, PT2, bar);
}

// Round 14
// 288.461 us; speedup vs baseline: 1.4808x; 1.4808x over previous
//
#include <hip/hip_runtime.h>
#include <math.h>

namespace {

constexpr int N_ = 1024;
constexpr int M_ = 1024;
constexpr int C_ = 64;
constexpr unsigned NBLK = 512;   // need 2 blocks/CU; LDS allows 4/CU -> 2x margin

typedef _Float16 f16x8 __attribute__((ext_vector_type(8)));
typedef __fp16 fp16x2 __attribute__((ext_vector_type(2)));   // cvt_pkrtz native type
typedef float f32x4 __attribute__((ext_vector_type(4)));

__device__ __forceinline__ float sig(float x) { return 1.0f / (1.0f + expf(-x)); }

__device__ __forceinline__ unsigned flipbits(float f) {
    unsigned u = __float_as_uint(f);
    return u ^ (0x80000000u | (unsigned)((int)u >> 31));
}
__device__ __forceinline__ float unflipbits(unsigned k) {
    unsigned u = (k & 0x80000000u) ? (k ^ 0x80000000u) : ~k;
    return __uint_as_float(u);
}
__device__ __forceinline__ unsigned long long packlogit(float v, unsigned idx) {
    return ((unsigned long long)flipbits(v) << 32) | (unsigned)(0xFFFFFFFFu - idx);
}
__device__ __forceinline__ unsigned long long packpos(float v, unsigned idx) {
    return ((unsigned long long)__float_as_uint(v) << 32) | (unsigned)(0xFFFFFFFFu - idx);
}
__device__ __forceinline__ unsigned long long shflx64(unsigned long long v, int m) {
    unsigned lo = __shfl_xor((unsigned)v, m);
    unsigned hi = __shfl_xor((unsigned)(v >> 32), m);
    return ((unsigned long long)hi << 32) | lo;
}

// hand-rolled grid barrier (counters zeroed by hipMemsetAsync before launch).
// KEY FIX vs round 11: spin with RELAXED polls (no per-iteration cache
// invalidate); a SINGLE acquire __threadfence after exit. The r11 version
// used ACQUIRE in the poll loop -> buffer_inv every iteration -> L1/L2
// invalidation storm (FETCH 11.4MB, VALUBusy 6.7%, dur 365us).
__device__ __forceinline__ void gridbar(unsigned* bar, unsigned target) {
    __syncthreads();
    if (threadIdx.x == 0) {
        __threadfence();    // agent-scope release of this block's stores
        __hip_atomic_fetch_add(bar, 1u, __ATOMIC_RELAXED, __HIP_MEMORY_SCOPE_AGENT);
        while (__hip_atomic_load(bar, __ATOMIC_RELAXED, __HIP_MEMORY_SCOPE_AGENT) < target)
            __builtin_amdgcn_s_sleep(16);
        __threadfence();    // single agent-scope acquire: drop stale lines once
    }
    __syncthreads();
}

// phase-overlaid LDS (union): biggest is phase B at 37.75 KB
struct SmemA { float XA[4][C_ + 1]; float XB[4][C_ + 1]; float W[C_ * C_]; float Bv[C_]; };
struct SmemB {
    float SU[32][68];                 // 8704 B
    float SVB[2][32][68];             // 17408 B (both zz staged once)
    float OUTT[32][33][2];            // 8448 B
    unsigned long long RED[8][32][2]; // 4096 B
};
struct SmemC { float h1s[4][C_]; };
union Smem { SmemA a; SmemB b; SmemC c; };

__global__ __launch_bounds__(256, 4) void fused_kernel(
    const float* __restrict__ step_x, const float* __restrict__ state_x,
    const float* __restrict__ w1, const float* __restrict__ b1,
    const float* __restrict__ w2, const float* __restrict__ b2,
    const float* __restrict__ w3, const float* __restrict__ b3,
    const float* __restrict__ pw1, const float* __restrict__ pb1,
    const float* __restrict__ pw2, const float* __restrict__ pb2,
    const float* __restrict__ pw3, const float* __restrict__ pb3,
    float* __restrict__ U, _Float16* __restrict__ w2T,
    unsigned long long* __restrict__ rowbest,
    float* __restrict__ out, unsigned long long* __restrict__ PT2,
    unsigned* __restrict__ bar)
{
    __shared__ Smem sm;
    const int t = threadIdx.x;
    const int bid = blockIdx.x;

    // ========== Phase A: pre-MLP (4 rows/block over 512 blocks) + w2T prep ==
    {
        SmemA& A = sm.a;
        const int r0 = bid * 4;            // rows r0..r0+3 (4 | 1024: no straddle)
        if (t < 64) {
            int rr = t >> 4, k4 = (t & 15) << 2;
            int row = r0 + rr;
            const float* src = (row < N_) ? (step_x + (size_t)row * C_ + k4)
                                          : (state_x + (size_t)(row - N_) * C_ + k4);
            float4 v = *reinterpret_cast<const float4*>(src);
            A.XA[rr][k4 + 0] = v.x; A.XA[rr][k4 + 1] = v.y;
            A.XA[rr][k4 + 2] = v.z; A.XA[rr][k4 + 3] = v.w;
        }
        if (bid >= 480 && bid < 496) {     // w2 -> transposed f16 (16 blocks)
            int e = (bid - 480) * 256 + t;
            w2T[(e & 63) * 64 + (e >> 6)] = (_Float16)pw2[e];
        }
        // rowbest + bar zeroed by the pre-launch hipMemsetAsync

        const float* Ws[4] = {w1, w2, w3, pw1};
        const float* Bs[4] = {b1, b2, b3, nullptr};
        float (*sA)[C_ + 1] = A.XA;
        float (*sB)[C_ + 1] = A.XB;
        const int c = t & 63;
        const int row = t >> 6;            // 0..3, one row per 64-thread group
        for (int layer = 0; layer < 4; ++layer) {
            __syncthreads();
            for (int e = t; e < C_ * C_ / 4; e += 256)
                reinterpret_cast<float4*>(A.W)[e] =
                    reinterpret_cast<const float4*>(Ws[layer])[e];
            if (t < C_) A.Bv[t] = (layer == 3) ? 0.0f : Bs[layer][t];
            __syncthreads();
            float acc = A.Bv[c];
            #pragma unroll 8
            for (int k = 0; k < C_; ++k)
                acc = fmaf(sA[row][k], A.W[k * C_ + c], acc);
            sB[row][c] = (layer < 2) ? fmaxf(acc, 0.0f) : acc;
            float (*tmp)[C_ + 1] = sA; sA = sB; sB = tmp;
        }
        U[(size_t)(r0 + row) * C_ + c] = sA[row][c];  // own writes only
    }
    gridbar(bar + 0, NBLK);

    // ========== Phase B: pair MLP, 2 tile-positions x 2 zz per block ========
    {
        SmemB& B = sm.b;
        const int lane = t & 63;
        const int wave = t >> 6;
        const int wi = wave >> 1, wj = wave & 1;
        const int ch_l = lane & 15;
        const int kg = lane >> 4;

        f16x8 whi[4][2];
        #pragma unroll
        for (int mt = 0; mt < 4; ++mt)
            #pragma unroll
            for (int ks = 0; ks < 2; ++ks)
                whi[mt][ks] = *reinterpret_cast<const f16x8*>(
                    w2T + (mt * 16 + ch_l) * 64 + ks * 32 + kg * 8);

        float b2v[16], w30[16], w31[16];
        #pragma unroll
        for (int mt = 0; mt < 4; ++mt)
            #pragma unroll
            for (int r = 0; r < 4; ++r) {
                int ch = mt * 16 + kg * 4 + r;
                b2v[mt * 4 + r] = pb2[ch];
                w30[mt * 4 + r] = pw3[ch * 2];
                w31[mt * 4 + r] = pw3[ch * 2 + 1];
            }
        const float ob0 = pb3[0], ob1 = pb3[1];

        for (int p = 0; p < 2; ++p) {
            const int tp = bid + p * 512;          // tile position 0..1023
            const int ibase = (tp >> 5) * 32;
            const int jbase = (tp & 31) * 32;

            __syncthreads();                       // protect LDS reuse across p
            {   // stage SU + SVB[0] (step) + SVB[1] (state), pb1 folded in
                const int r = t >> 3, k0 = (t & 7) * 8;
                const float* up = U + (size_t)(ibase + r) * C_ + k0;
                *reinterpret_cast<float4*>(&B.SU[r][k0])     = *reinterpret_cast<const float4*>(up);
                *reinterpret_cast<float4*>(&B.SU[r][k0 + 4]) = *reinterpret_cast<const float4*>(up + 4);
                float4 c0 = *reinterpret_cast<const float4*>(pb1 + k0);
                float4 c1 = *reinterpret_cast<const float4*>(pb1 + k0 + 4);
                #pragma unroll
                for (int zzv = 0; zzv < 2; ++zzv) {
                    const float* vp = U + (size_t)(zzv * N_ + jbase + r) * C_ + k0;
                    float4 b0 = *reinterpret_cast<const float4*>(vp);
                    float4 b1v = *reinterpret_cast<const float4*>(vp + 4);
                    b0.x += c0.x; b0.y += c0.y; b0.z += c0.z; b0.w += c0.w;
                    b1v.x += c1.x; b1v.y += c1.y; b1v.z += c1.z; b1v.w += c1.w;
                    *reinterpret_cast<float4*>(&B.SVB[zzv][r][k0])     = b0;
                    *reinterpret_cast<float4*>(&B.SVB[zzv][r][k0 + 4]) = b1v;
                }
            }
            __syncthreads();

            float su[2][8];
            #pragma unroll
            for (int ks = 0; ks < 2; ++ks) {
                int k0 = ks * 32 + kg * 8;
                float4 a = *reinterpret_cast<const float4*>(&B.SU[wi * 16 + ch_l][k0]);
                float4 b = *reinterpret_cast<const float4*>(&B.SU[wi * 16 + ch_l][k0 + 4]);
                su[ks][0] = a.x; su[ks][1] = a.y; su[ks][2] = a.z; su[ks][3] = a.w;
                su[ks][4] = b.x; su[ks][5] = b.y; su[ks][6] = b.z; su[ks][7] = b.w;
            }

            for (int zzv = 0; zzv < 2; ++zzv) {
                if (zzv) __syncthreads();          // protect OUTT reuse across zz
                for (int jj = 0; jj < 16; ++jj) {
                    const int jr = wj * 16 + jj;
                    f16x8 bhi[2];
                    #pragma unroll
                    for (int ks = 0; ks < 2; ++ks) {
                        int k0 = ks * 32 + kg * 8;
                        float4 a = *reinterpret_cast<const float4*>(&B.SVB[zzv][jr][k0]);
                        float4 b = *reinterpret_cast<const float4*>(&B.SVB[zzv][jr][k0 + 4]);
                        float sv[8] = {a.x, a.y, a.z, a.w, b.x, b.y, b.z, b.w};
                        union { f16x8 v; fp16x2 h2[4]; } bu;
                        #pragma unroll
                        for (int m = 0; m < 4; ++m) {
                            float x0 = fmaxf(su[ks][2 * m]     + sv[2 * m],     0.0f);
                            float x1 = fmaxf(su[ks][2 * m + 1] + sv[2 * m + 1], 0.0f);
                            bu.h2[m] = __builtin_amdgcn_cvt_pkrtz(x0, x1);
                        }
                        bhi[ks] = bu.v;
                    }
                    f32x4 ah[4];
                    #pragma unroll
                    for (int mt = 0; mt < 4; ++mt)
                        ah[mt] = f32x4{b2v[4 * mt], b2v[4 * mt + 1], b2v[4 * mt + 2], b2v[4 * mt + 3]};
                    #pragma unroll
                    for (int ks = 0; ks < 2; ++ks)
                        #pragma unroll
                        for (int mt = 0; mt < 4; ++mt)
                            ah[mt] = __builtin_amdgcn_mfma_f32_16x16x32_f16(whi[mt][ks], bhi[ks], ah[mt], 0, 0, 0);
                    float p0 = 0.0f, p1 = 0.0f;
                    #pragma unroll
                    for (int mt = 0; mt < 4; ++mt)
                        #pragma unroll
                        for (int r = 0; r < 4; ++r) {
                            float g = fmaxf(ah[mt][r], 0.0f);
                            p0 = fmaf(g, w30[4 * mt + r], p0);
                            p1 = fmaf(g, w31[4 * mt + r], p1);
                        }
                    p0 += __shfl_xor(p0, 16); p0 += __shfl_xor(p0, 32);
                    p1 += __shfl_xor(p1, 16); p1 += __shfl_xor(p1, 32);
                    if (lane < 16) {
                        B.OUTT[wi * 16 + lane][wj * 16 + jj][0] = p0 + ob0;
                        B.OUTT[wi * 16 + lane][wj * 16 + jj][1] = p1 + ob1;
                    }
                }
                __syncthreads();
                {   // writeout tile
                    float* obase = out + (size_t)zzv * (2ull * N_ * M_);
                    int r = t >> 3;
                    int q0 = (t & 7) * 4;
                    int i = ibase + r;
                    #pragma unroll
                    for (int q = 0; q < 4; ++q) {
                        int j = jbase + q0 + q;
                        float2 v = *reinterpret_cast<float2*>(&B.OUTT[r][q0 + q][0]);
                        *reinterpret_cast<float2*>(obase + ((size_t)i * M_ + j) * 2) = v;
                    }
                }
                if (zzv) {   // fused column top-2 over this tile's 32 rows (st logit)
                    const int tc = t & 31, tg = t >> 5;
                    unsigned long long k1 = 0, k2 = 0;
                    #pragma unroll
                    for (int q = 0; q < 4; ++q) {
                        int r = tg * 4 + q;
                        unsigned long long k = packlogit(B.OUTT[r][tc][0], (unsigned)(ibase + r));
                        if (k > k1) { k2 = k1; k1 = k; } else if (k > k2) k2 = k;
                    }
                    B.RED[tg][tc][0] = k1; B.RED[tg][tc][1] = k2;
                    for (int h = 4; h > 0; h >>= 1) {
                        __syncthreads();
                        if (tg < h) {
                            unsigned long long a = B.RED[tg + h][tc][0], b = B.RED[tg + h][tc][1];
                            if (a > k1) { k2 = k1; k1 = a; } else if (a > k2) k2 = a;
                            if (b > k1) { k2 = k1; k1 = b; } else if (b > k2) k2 = b;
                            B.RED[tg][tc][0] = k1; B.RED[tg][tc][1] = k2;
                        }
                    }
                    if (tg == 0) {
                        size_t o = ((size_t)(tp >> 5) * M_ + (jbase + tc)) * 2;
                        PT2[o] = k1; PT2[o + 1] = k2;
                    }
                }
            }
        }
    }
    gridbar(bar + 1, NBLK);

    // ========== Phase C: column finalize (blocks 0..255, 4 cols each) =======
    if (bid < 256) {
        SmemC& Cc = sm.c;
        const int w = t >> 6, lane = t & 63;
        const int j = bid * 4 + w;

        unsigned long long k1 = PT2[((size_t)(lane >> 1) * M_ + j) * 2 + (lane & 1)];
        unsigned long long k2 = 0;
        #pragma unroll
        for (int m = 1; m < 64; m <<= 1) {
            unsigned long long a = shflx64(k1, m), b = shflx64(k2, m);
            if (a > k1) { k2 = k1; k1 = a; } else if (a > k2) k2 = a;
            if (b > k1) { k2 = k1; k1 = b; } else if (b > k2) k2 = b;
        }
        int ids[2];
        ids[0] = (int)(0xFFFFFFFFu - (unsigned)(k1 & 0xFFFFFFFFull));
        int i2 = (int)(0xFFFFFFFFu - (unsigned)(k2 & 0xFFFFFFFFull));
        float v1 = unflipbits((unsigned)(k1 >> 32));
        float v2 = unflipbits((unsigned)(k2 >> 32));
        // uniform 2 candidates (dup winner when no near-tie): __syncthreads legal
        ids[1] = (v1 - v2 < 8e-3f) ? i2 : ids[0];

        float logits[2];
        #pragma unroll
        for (int cnd = 0; cnd < 2; ++cnd) {
            int i = ids[cnd];
            Cc.h1s[w][lane] = fmaxf(U[(size_t)i * C_ + lane] + U[(size_t)(N_ + j) * C_ + lane] + pb1[lane], 0.0f);
            __syncthreads();
            float acc = pb2[lane];
            #pragma unroll 8
            for (int k = 0; k < 64; ++k)
                acc = fmaf(Cc.h1s[w][k], pw2[k * 64 + lane], acc);
            float p = fmaxf(acc, 0.0f) * pw3[lane * 2];
            #pragma unroll
            for (int m = 1; m < 64; m <<= 1) p += __shfl_xor(p, m);
            logits[cnd] = p + pb3[0];
            __syncthreads();
        }
        int wi2; float wp;
        if (logits[0] > logits[1])      { wi2 = ids[0]; wp = logits[0]; }
        else if (logits[1] > logits[0]) { wi2 = ids[1]; wp = logits[1]; }
        else                            { wi2 = min(ids[0], ids[1]); wp = logits[0]; }
        if (lane == 0)
            atomicMax(&rowbest[wi2], packpos(sig(wp), (unsigned)j));
    }
    gridbar(bar + 2, NBLK);

    // ========== Phase D: zero matched rows + scatter mutual matches =========
    {
        float* matched = out + 4ull * N_ * M_;
        #pragma unroll
        for (int rr = 0; rr < 2; ++rr) {
            int i = bid * 2 + rr;
            *reinterpret_cast<float4*>(matched + (size_t)i * M_ + t * 4) =
                float4{0.0f, 0.0f, 0.0f, 0.0f};
        }
        __syncthreads();
        if (t < 2) {
            int i = bid * 2 + t;
            unsigned long long key = rowbest[i];
            if (key) {
                unsigned j = 0xFFFFFFFFu - (unsigned)(key & 0xFFFFFFFFull);
                matched[(size_t)i * M_ + j] = __uint_as_float((unsigned)(key >> 32));
            }
        }
    }
}

} // namespace

extern "C" void kernel_launch(void* const* d_in, const int* in_sizes, int n_in,
                              void* d_out, int out_size, void* d_ws, size_t ws_size,
                              hipStream_t stream)
{
    const float* step_x  = (const float*)d_in[0];
    const float* state_x = (const float*)d_in[1];
    const float* pre_w1  = (const float*)d_in[2];
    const float* pre_b1  = (const float*)d_in[3];
    const float* pre_w2  = (const float*)d_in[4];
    const float* pre_b2  = (const float*)d_in[5];
    const float* pre_w3  = (const float*)d_in[6];
    const float* pre_b3  = (const float*)d_in[7];
    const float* post_w1 = (const float*)d_in[8];
    const float* post_b1 = (const float*)d_in[9];
    const float* post_w2 = (const float*)d_in[10];
    const float* post_b2 = (const float*)d_in[11];
    const float* post_w3 = (const float*)d_in[12];
    const float* post_b3 = (const float*)d_in[13];

    float* out     = (float*)d_out;
    float* matched = out + 4ull * N_ * M_;

    // ws: U (512KB) + rowbest (8KB) + barrier counters (12B)
    float* U = (float*)d_ws;
    unsigned long long* rowbest = (unsigned long long*)((char*)d_ws + 512 * 1024);
    unsigned* bar = (unsigned*)((char*)d_ws + 520 * 1024);

    // scratch inside 'matched' (4MB), fully consumed before phase D rewrites it
    unsigned long long* PT2 = (unsigned long long*)matched;       // 512KB (B->C)
    _Float16* w2T = (_Float16*)((char*)matched + 512 * 1024);     // 8KB  (A->B)

    // zero rowbest + barrier counters (capturable memset node)
    hipMemsetAsync((char*)d_ws + 512 * 1024, 0, 8 * 1024 + 16, stream);

    hipLaunchKernelGGL(fused_kernel, dim3(NBLK), dim3(256), 0, stream,
        step_x, state_x, pre_w1, pre_b1, pre_w2, pre_b2, pre_w3, pre_b3,
        post_w1, post_b1, post_w2, post_b2, post_w3, post_b3,
        U, w2T, rowbest, out, PT2, bar);
}